// Round 6
// baseline (83.627 us; speedup 1.0000x reference)
//
#include <hip/hip_runtime.h>

// 3D median 3x3x3, zero pad, exact. Round 6: occupancy experiment.
// Same selection as R5 (band-stat pruning -> antichain exclusions ->
// triple-structured forgetful, absmax 0.0 verified). Structural changes:
// - No z-strip / no Y plane cache: live set ~ V[9][6] + sel temps -> fits
//   128 VGPRs; __launch_bounds__(256,4) enforces 4 waves/SIMD (R5 was ~2).
// - Block-uniform interior/boundary specialization: interior blocks (94%)
//   skip all z/y clamps and cndmasks; x-halo loads use raw w0-1 / w0+4
//   (in-bounds neighboring-row elements; garbage masked by lane cndmask).

#define MIN3(a, b, c) fminf(fminf(a, b), c)
#define MAX3(a, b, c) fmaxf(fmaxf(a, b), c)
#define MED3(a, b, c) __builtin_amdgcn_fmed3f(a, b, c)

__device__ __forceinline__ void sort3(float &a, float &b, float &c) {
    float lo = MIN3(a, b, c);
    float hi = MAX3(a, b, c);
    float md = MED3(a, b, c);
    a = lo; b = md; c = hi;
}

// Exact median of 27 given V[line=zr*3+yr][col], lines z/y sorted; cols
// o..o+2. Band-stat prune (19) -> antichain exclusions (15, rank 8) ->
// triple-forgetful -> med9. Verified exact (0-1 principle + absmax 0.0).
__device__ __forceinline__ float sel19(const float V[9][6], int o) {
    float a0h = MAX3(V[0][o], V[0][o + 1], V[0][o + 2]);
    float a1m = MED3(V[1][o], V[1][o + 1], V[1][o + 2]);
    float a1h = MAX3(V[1][o], V[1][o + 1], V[1][o + 2]);
    float a2l = V[2][o], a2m = V[2][o + 1], a2h = V[2][o + 2];
    sort3(a2l, a2m, a2h);
    float b0m = MED3(V[3][o], V[3][o + 1], V[3][o + 2]);
    float b0h = MAX3(V[3][o], V[3][o + 1], V[3][o + 2]);
    float b1l = V[4][o], b1m = V[4][o + 1], b1h = V[4][o + 2];
    sort3(b1l, b1m, b1h);
    float b2l = MIN3(V[5][o], V[5][o + 1], V[5][o + 2]);
    float b2m = MED3(V[5][o], V[5][o + 1], V[5][o + 2]);
    float c0l = V[6][o], c0m = V[6][o + 1], c0h = V[6][o + 2];
    sort3(c0l, c0m, c0h);
    float c1l = MIN3(V[7][o], V[7][o + 1], V[7][o + 2]);
    float c1m = MED3(V[7][o], V[7][o + 1], V[7][o + 2]);
    float c2l = MIN3(V[8][o], V[8][o + 1], V[8][o + 2]);

    float pa = a1m, pb = b0m, pc = b1l; sort3(pa, pb, pc);  // pa <= med
    float qa = b1h, qb = b2m, qc = c1m; sort3(qa, qb, qc);  // qc >= med
    float ra = a0h, rb = a2l, rc = c0l; sort3(ra, rb, rc);  // ra <= med
    float sa = a2h, sb = c0h, sc = c2l; sort3(sa, sb, sc);  // sc >= med
    (void)pa; (void)qc; (void)ra; (void)sc;

    float t1l = pb, t1m = pc, t1h = b1m;                    // free-sorted
    float t2l = rb, t2m = rc, t2h = a1h; sort3(t2l, t2m, t2h);
    float t3l = sa, t3m = sb, t3h = c1l; sort3(t3l, t3m, t3h);
    {
        float lam1 = MED3(t1l, t2l, t3l), lam2 = MAX3(t1l, t2l, t3l);
        float eta1 = MIN3(t1h, t2h, t3h), eta2 = MED3(t1h, t2h, t3h);
        float mu1 = t1m, mu2 = t2m, mu3 = t3m;
        t1l = lam1; t1m = lam2; t1h = qa; sort3(t1l, t1m, t1h);
        t2l = mu1;  t2m = mu2;  t2h = mu3; sort3(t2l, t2m, t2h);
        t3l = eta1; t3m = eta2; t3h = qb; sort3(t3l, t3m, t3h);
    }
    {
        float lam1 = MED3(t1l, t2l, t3l), lam2 = MAX3(t1l, t2l, t3l);
        float eta1 = MIN3(t1h, t2h, t3h), eta2 = MED3(t1h, t2h, t3h);
        float mu1 = t1m, mu2 = t2m, mu3 = t3m;
        t1l = lam1; t1m = lam2; t1h = a2m; sort3(t1l, t1m, t1h);
        t2l = mu1;  t2m = mu2;  t2h = mu3; sort3(t2l, t2m, t2h);
        t3l = eta1; t3m = eta2; t3h = c0m; sort3(t3l, t3m, t3h);
    }
    {
        float lam1 = MED3(t1l, t2l, t3l), lam2 = MAX3(t1l, t2l, t3l);
        float eta1 = MIN3(t1h, t2h, t3h), eta2 = MED3(t1h, t2h, t3h);
        float mu1 = t1m, mu2 = t2m, mu3 = t3m;
        t1l = lam1; t1m = lam2; t1h = b0h; sort3(t1l, t1m, t1h);
        t2l = mu1;  t2m = mu2;  t2h = mu3; sort3(t2l, t2m, t2h);
        t3l = eta1; t3m = eta2; t3h = b2l; sort3(t3l, t3m, t3h);
    }
    return MED3(MAX3(t1l, t2l, t3l), MED3(t1m, t2m, t3m),
                MIN3(t1h, t2h, t3h));
}

__global__ __launch_bounds__(256, 4) void median3d_kernel(
    const float *__restrict__ x, float *__restrict__ out) {
    const int W = 256, H = 256, D = 64;
    const int lane = threadIdx.x;   // wave spans full 256-wide x row
    const int w0 = lane << 2;       // 4 x-outputs
    const int h = blockIdx.y * 4 + threadIdx.y;
    const int d = blockIdx.z;
    const bool lval = (lane != 0), rval = (lane != 63);

    float V[9][6];
    const bool interior = (blockIdx.y != 0) && (blockIdx.y != gridDim.y - 1) &&
                          (d != 0) && (d != D - 1);
    if (interior) {
        // No z/y masking. x halo loads unclamped: rowp[-1] / rowp[256] are
        // in-bounds neighboring-row elements, masked off by lane cndmask.
#pragma unroll
        for (int dz = 0; dz < 3; ++dz)
#pragma unroll
            for (int dy = 0; dy < 3; ++dy) {
                const float *rowp =
                    x + (size_t)((d + dz - 1) * H + (h + dy - 1)) * W;
                const float l = rowp[w0 - 1];
                const float4 m = *(const float4 *)(rowp + w0);
                const float r = rowp[w0 + 4];
                const int L = dz * 3 + dy;
                V[L][0] = lval ? l : 0.0f;
                V[L][1] = m.x; V[L][2] = m.y; V[L][3] = m.z; V[L][4] = m.w;
                V[L][5] = rval ? r : 0.0f;
            }
    } else {
        const int wl = (lane == 0) ? 0 : (w0 - 1);
        const int wr = (lane == 63) ? (W - 1) : (w0 + 4);
#pragma unroll
        for (int dz = 0; dz < 3; ++dz) {
            const int dd = d + dz - 1;
            const bool zok = (unsigned)dd < (unsigned)D;
            const int dc = zok ? dd : 0;
#pragma unroll
            for (int dy = 0; dy < 3; ++dy) {
                const int hh = h + dy - 1;
                const bool hok = (unsigned)hh < (unsigned)H;
                const int hc = hok ? hh : 0;
                const bool ok = zok && hok;
                const float *rowp = x + (size_t)(dc * H + hc) * W;
                const float l = rowp[wl];
                const float4 m = *(const float4 *)(rowp + w0);
                const float r = rowp[wr];
                const int L = dz * 3 + dy;
                V[L][0] = (ok && lval) ? l : 0.0f;
                V[L][1] = ok ? m.x : 0.0f;
                V[L][2] = ok ? m.y : 0.0f;
                V[L][3] = ok ? m.z : 0.0f;
                V[L][4] = ok ? m.w : 0.0f;
                V[L][5] = (ok && rval) ? r : 0.0f;
            }
        }
    }

    // z-sort (lines y fixed) then y-sort, all 6 columns.
#pragma unroll
    for (int y = 0; y < 3; ++y)
#pragma unroll
        for (int c = 0; c < 6; ++c)
            sort3(V[0 + y][c], V[3 + y][c], V[6 + y][c]);
#pragma unroll
    for (int z = 0; z < 3; ++z)
#pragma unroll
        for (int c = 0; c < 6; ++c)
            sort3(V[3 * z + 0][c], V[3 * z + 1][c], V[3 * z + 2][c]);

    float4 r4;
    r4.x = sel19(V, 0);
    r4.y = sel19(V, 1);
    r4.z = sel19(V, 2);
    r4.w = sel19(V, 3);
    *(float4 *)(out + (size_t)(d * H + h) * W + w0) = r4;
}

extern "C" void kernel_launch(void *const *d_in, const int *in_sizes, int n_in,
                              void *d_out, int out_size, void *d_ws,
                              size_t ws_size, hipStream_t stream) {
    const float *x = (const float *)d_in[0];
    float *out = (float *)d_out;
    dim3 block(64, 4, 1);
    dim3 grid(1, 256 / 4, 64);
    median3d_kernel<<<grid, block, 0, stream>>>(x, out);
}

// Round 7
// 79.823 us; speedup vs baseline: 1.0476x; 1.0476x over previous
//
#include <hip/hip_runtime.h>

// 3D median 3x3x3, zero pad, exact. Round 7: R5 algorithm (y-sort -> z-sort
// -> band-stat prune 19 -> antichain exclude to rank-8-of-15 ->
// triple-structured forgetful -> med9; absmax 0.0 in R1-R6) with a
// ROLLING-plane z-strip of 4:
// - y-stats kept in a circular 3-plane buffer (live set independent of strip
//   length, unlike R5's 4-plane cache) -> ~145 VGPRs, ~3 waves/SIMD.
// - 6 planes serve 4 z-outputs: 1.5 plane-loads+y-sorts per z-output
//   (R5: 2.0), addressing/masking amortized over 16 outputs/thread.

#define MIN3(a, b, c) fminf(fminf(a, b), c)
#define MAX3(a, b, c) fmaxf(fmaxf(a, b), c)
#define MED3(a, b, c) __builtin_amdgcn_fmed3f(a, b, c)

__device__ __forceinline__ void sort3(float &a, float &b, float &c) {
    float lo = MIN3(a, b, c);
    float hi = MAX3(a, b, c);
    float md = MED3(a, b, c);
    a = lo; b = md; c = hi;
}

// Exact median of 27 given V[line=zr*3+yr][col], z/y sorted; cols o..o+2.
__device__ __forceinline__ float sel19(const float V[9][6], int o) {
    float a0h = MAX3(V[0][o], V[0][o + 1], V[0][o + 2]);
    float a1m = MED3(V[1][o], V[1][o + 1], V[1][o + 2]);
    float a1h = MAX3(V[1][o], V[1][o + 1], V[1][o + 2]);
    float a2l = V[2][o], a2m = V[2][o + 1], a2h = V[2][o + 2];
    sort3(a2l, a2m, a2h);
    float b0m = MED3(V[3][o], V[3][o + 1], V[3][o + 2]);
    float b0h = MAX3(V[3][o], V[3][o + 1], V[3][o + 2]);
    float b1l = V[4][o], b1m = V[4][o + 1], b1h = V[4][o + 2];
    sort3(b1l, b1m, b1h);
    float b2l = MIN3(V[5][o], V[5][o + 1], V[5][o + 2]);
    float b2m = MED3(V[5][o], V[5][o + 1], V[5][o + 2]);
    float c0l = V[6][o], c0m = V[6][o + 1], c0h = V[6][o + 2];
    sort3(c0l, c0m, c0h);
    float c1l = MIN3(V[7][o], V[7][o + 1], V[7][o + 2]);
    float c1m = MED3(V[7][o], V[7][o + 1], V[7][o + 2]);
    float c2l = MIN3(V[8][o], V[8][o + 1], V[8][o + 2]);

    // Antichain exclusions (rank certificates; min/max results of the
    // unused extremes are dead-code-eliminated):
    float pa = a1m, pb = b0m, pc = b1l; sort3(pa, pb, pc);  // pa <= med
    float qa = b1h, qb = b2m, qc = c1m; sort3(qa, qb, qc);  // qc >= med
    float ra = a0h, rb = a2l, rc = c0l; sort3(ra, rb, rc);  // ra <= med
    float sa = a2h, sb = c0h, sc = c2l; sort3(sa, sb, sc);  // sc >= med
    (void)pa; (void)qc; (void)ra; (void)sc;

    float t1l = pb, t1m = pc, t1h = b1m;                    // free-sorted
    float t2l = rb, t2m = rc, t2h = a1h; sort3(t2l, t2m, t2h);
    float t3l = sa, t3m = sb, t3h = c1l; sort3(t3l, t3m, t3h);
    {
        float lam1 = MED3(t1l, t2l, t3l), lam2 = MAX3(t1l, t2l, t3l);
        float eta1 = MIN3(t1h, t2h, t3h), eta2 = MED3(t1h, t2h, t3h);
        float mu1 = t1m, mu2 = t2m, mu3 = t3m;
        t1l = lam1; t1m = lam2; t1h = qa; sort3(t1l, t1m, t1h);
        t2l = mu1;  t2m = mu2;  t2h = mu3; sort3(t2l, t2m, t2h);
        t3l = eta1; t3m = eta2; t3h = qb; sort3(t3l, t3m, t3h);
    }
    {
        float lam1 = MED3(t1l, t2l, t3l), lam2 = MAX3(t1l, t2l, t3l);
        float eta1 = MIN3(t1h, t2h, t3h), eta2 = MED3(t1h, t2h, t3h);
        float mu1 = t1m, mu2 = t2m, mu3 = t3m;
        t1l = lam1; t1m = lam2; t1h = a2m; sort3(t1l, t1m, t1h);
        t2l = mu1;  t2m = mu2;  t2h = mu3; sort3(t2l, t2m, t2h);
        t3l = eta1; t3m = eta2; t3h = c0m; sort3(t3l, t3m, t3h);
    }
    {
        float lam1 = MED3(t1l, t2l, t3l), lam2 = MAX3(t1l, t2l, t3l);
        float eta1 = MIN3(t1h, t2h, t3h), eta2 = MED3(t1h, t2h, t3h);
        float mu1 = t1m, mu2 = t2m, mu3 = t3m;
        t1l = lam1; t1m = lam2; t1h = b0h; sort3(t1l, t1m, t1h);
        t2l = mu1;  t2m = mu2;  t2h = mu3; sort3(t2l, t2m, t2h);
        t3l = eta1; t3m = eta2; t3h = b2l; sort3(t3l, t3m, t3h);
    }
    return MED3(MAX3(t1l, t2l, t3l), MED3(t1m, t2m, t3m),
                MIN3(t1h, t2h, t3h));
}

__global__ __launch_bounds__(256) void median3d_kernel(
    const float *__restrict__ x, float *__restrict__ out) {
    const int W = 256, H = 256, D = 64;
    const int lane = threadIdx.x;   // wave spans full 256-wide x row
    const int w0 = lane << 2;       // 4 x-outputs
    const int h = blockIdx.y * 4 + threadIdx.y;
    const int d0 = blockIdx.z * 4;  // 4 z-outputs: d0..d0+3
    const int wl = (lane == 0) ? 0 : (w0 - 1);
    const int wr = (lane == 63) ? (W - 1) : (w0 + 4);
    const bool lval = (lane != 0), rval = (lane != 63);

    // Circular y-stat buffer: Yst[slot][ystat][col], slot = plane % 3.
    float Yst[3][3][6];

    // Load plane dd = d0 + p - 1 (p = 0..5) into slot, y-sorted.
#define LOADPLANE(P, SLOT)                                                   \
    do {                                                                     \
        const int dd = d0 + (P)-1;                                           \
        const bool zok = (unsigned)dd < (unsigned)D;                         \
        const int dc = zok ? dd : 0;                                         \
        float r[3][6];                                                       \
        _Pragma("unroll") for (int dy = 0; dy < 3; ++dy) {                   \
            const int hh = h + dy - 1;                                       \
            const bool hok = (unsigned)hh < (unsigned)H;                     \
            const int hc = hok ? hh : 0;                                     \
            const bool ok = zok && hok;                                      \
            const float *rowp = x + (size_t)(dc * H + hc) * W;               \
            const float l = rowp[wl];                                        \
            const float4 m = *(const float4 *)(rowp + w0);                   \
            const float rr = rowp[wr];                                       \
            r[dy][0] = (ok && lval) ? l : 0.0f;                              \
            r[dy][1] = ok ? m.x : 0.0f;                                      \
            r[dy][2] = ok ? m.y : 0.0f;                                      \
            r[dy][3] = ok ? m.z : 0.0f;                                      \
            r[dy][4] = ok ? m.w : 0.0f;                                      \
            r[dy][5] = (ok && rval) ? rr : 0.0f;                             \
        }                                                                    \
        _Pragma("unroll") for (int c = 0; c < 6; ++c) {                      \
            sort3(r[0][c], r[1][c], r[2][c]);                                \
            Yst[SLOT][0][c] = r[0][c];                                       \
            Yst[SLOT][1][c] = r[1][c];                                       \
            Yst[SLOT][2][c] = r[2][c];                                       \
        }                                                                    \
    } while (0)

    LOADPLANE(0, 0);
    LOADPLANE(1, 1);

#pragma unroll
    for (int zo = 0; zo < 4; ++zo) {
        // Bring in plane zo+2 (slot (zo+2)%3), overwriting the expired one.
        switch ((zo + 2) % 3) {
            case 0: LOADPLANE(zo + 2, 0); break;
            case 1: LOADPLANE(zo + 2, 1); break;
            default: LOADPLANE(zo + 2, 2); break;
        }
        const int sA = zo % 3, sB = (zo + 1) % 3, sC = (zo + 2) % 3;
        // z-sort the 3 y-stats across the window planes -> V lines.
        float V[9][6];
#pragma unroll
        for (int yr = 0; yr < 3; ++yr)
#pragma unroll
            for (int c = 0; c < 6; ++c) {
                float a = Yst[sA][yr][c];
                float b = Yst[sB][yr][c];
                float cc = Yst[sC][yr][c];
                sort3(a, b, cc);
                V[0 + yr][c] = a;
                V[3 + yr][c] = b;
                V[6 + yr][c] = cc;
            }
        float4 r4;
        r4.x = sel19(V, 0);
        r4.y = sel19(V, 1);
        r4.z = sel19(V, 2);
        r4.w = sel19(V, 3);
        *(float4 *)(out + (size_t)((d0 + zo) * H + h) * W + w0) = r4;
    }
#undef LOADPLANE
}

extern "C" void kernel_launch(void *const *d_in, const int *in_sizes, int n_in,
                              void *d_out, int out_size, void *d_ws,
                              size_t ws_size, hipStream_t stream) {
    const float *x = (const float *)d_in[0];
    float *out = (float *)d_out;
    dim3 block(64, 4, 1);
    dim3 grid(1, 256 / 4, 64 / 4);
    median3d_kernel<<<grid, block, 0, stream>>>(x, out);
}